// Round 1
// baseline (655.564 us; speedup 1.0000x reference)
//
#include <hip/hip_runtime.h>
#include <hip/hip_bf16.h>
#include <cstdint>
#include <cstddef>

// Problem constants
#define BB 4
#define SS 2048
#define EE 1024
#define HH 16
#define DD 64
// M = BB*SS = 8192

typedef __attribute__((ext_vector_type(8))) short bf16x8;
typedef __attribute__((ext_vector_type(4))) float f32x4;

__device__ __forceinline__ short f2bf(float f) {
    union { float f; uint32_t u; } x; x.f = f;
    uint32_t r = (x.u + 0x7fffu + ((x.u >> 16) & 1u)) >> 16;
    return (short)r;
}

__global__ void cast_kernel(const float* __restrict__ in, short* __restrict__ out, int n4) {
    int stride = gridDim.x * blockDim.x;
    for (int i = blockIdx.x * blockDim.x + threadIdx.x; i < n4; i += stride) {
        float4 v = reinterpret_cast<const float4*>(in)[i];
        short4 o;
        o.x = f2bf(v.x); o.y = f2bf(v.y); o.z = f2bf(v.z); o.w = f2bf(v.w);
        reinterpret_cast<short4*>(out)[i] = o;
    }
}

// C = A[M,K] * B[K,N]; 128x128 block tile, 4 waves (2x2), each wave 64x64 (4x4 frags of 16x16x32)
// MODE 0: QKV epilogue (bias add, Q scaled 0.125, scatter to Q/K/V [B*H][S][D] bf16)
// MODE 1: proj epilogue (bias add, fp32 out row-major [M][N])
template<int MODE, int N, int K>
__global__ __launch_bounds__(256, 2)
void gemm_kernel(const short* __restrict__ A, const short* __restrict__ Bm,
                 const float* __restrict__ bias,
                 short* __restrict__ Qo, short* __restrict__ Ko, short* __restrict__ Vo,
                 float* __restrict__ Co)
{
    __shared__ short As[128][40];   // [m][k], pad 32->40 (2-way free)
    __shared__ short Bs[128][40];   // [n][k] transposed store
    const int tid  = threadIdx.x;
    const int lane = tid & 63, wid = tid >> 6;
    const int wr = wid >> 1, wc = wid & 1;
    const int l15 = lane & 15, lhi = lane >> 4;
    const int m0 = blockIdx.y * 128, n0 = blockIdx.x * 128;

    f32x4 acc[4][4] = {};

    for (int kt = 0; kt < K / 32; ++kt) {
        // stage A: 128 rows x 32 k
        #pragma unroll
        for (int p = 0; p < 2; ++p) {
            int row = (tid >> 2) + p * 64;
            int kc  = (tid & 3) * 8;
            bf16x8 v = *reinterpret_cast<const bf16x8*>(&A[(size_t)(m0 + row) * K + kt * 32 + kc]);
            *reinterpret_cast<bf16x8*>(&As[row][kc]) = v;
        }
        // stage B transposed: read B[k][n] coalesced, write Bs[n][k]
        #pragma unroll
        for (int p = 0; p < 2; ++p) {
            int krow = (tid >> 4) + p * 16;
            int nc   = (tid & 15) * 8;
            bf16x8 v = *reinterpret_cast<const bf16x8*>(&Bm[(size_t)(kt * 32 + krow) * N + n0 + nc]);
            #pragma unroll
            for (int j = 0; j < 8; ++j) Bs[nc + j][krow] = v[j];
        }
        __syncthreads();

        bf16x8 af[4], bfr[4];
        #pragma unroll
        for (int mm = 0; mm < 4; ++mm)
            af[mm] = *reinterpret_cast<const bf16x8*>(&As[wr * 64 + mm * 16 + l15][lhi * 8]);
        #pragma unroll
        for (int nn = 0; nn < 4; ++nn)
            bfr[nn] = *reinterpret_cast<const bf16x8*>(&Bs[wc * 64 + nn * 16 + l15][lhi * 8]);
        #pragma unroll
        for (int mm = 0; mm < 4; ++mm)
            #pragma unroll
            for (int nn = 0; nn < 4; ++nn)
                acc[mm][nn] = __builtin_amdgcn_mfma_f32_16x16x32_bf16(af[mm], bfr[nn], acc[mm][nn], 0, 0, 0);
        __syncthreads();
    }

    // epilogue: C row = (lane>>4)*4 + r, col = lane&15  (m89-verified layout)
    #pragma unroll
    for (int mm = 0; mm < 4; ++mm) {
        #pragma unroll
        for (int nn = 0; nn < 4; ++nn) {
            int gcol = n0 + wc * 64 + nn * 16 + l15;
            float bv = bias[gcol];
            #pragma unroll
            for (int r = 0; r < 4; ++r) {
                int grow = m0 + wr * 64 + mm * 16 + lhi * 4 + r;
                float val = acc[mm][nn][r] + bv;
                if (MODE == 0) {
                    int part = gcol >> 10;       // 0=q 1=k 2=v
                    int e = gcol & 1023;
                    int h = e >> 6, d = e & 63;
                    int bidx = grow >> 11;       // /S
                    int s = grow & 2047;
                    size_t idx = ((size_t)(bidx * HH + h) * SS + s) * DD + d;
                    if (part == 0)      Qo[idx] = f2bf(val * 0.125f);  // fold 1/sqrt(D)
                    else if (part == 1) Ko[idx] = f2bf(val);
                    else                Vo[idx] = f2bf(val);
                } else {
                    Co[(size_t)grow * EE + gcol] = val;
                }
            }
        }
    }
}

// Flash attention: grid (S/64, B*H); 4 waves, each owns 16 q-rows; k-tiles of 32
__global__ __launch_bounds__(256, 2)
void attn_kernel(const short* __restrict__ Q, const short* __restrict__ K,
                 const short* __restrict__ V, short* __restrict__ CTX)
{
    __shared__ short Vt[64][40];        // [d][kj] transposed V tile, pad 40
    __shared__ short Plds[4][16][40];   // per-wave P tile [q][kj]
    const int tid  = threadIdx.x;
    const int lane = tid & 63, wid = tid >> 6;
    const int l15 = lane & 15, lhi = lane >> 4;
    const int bh = blockIdx.y;
    const int q0 = blockIdx.x * 64;
    const int qbase = q0 + wid * 16;
    const size_t base = (size_t)bh * SS * DD;

    // Q fragments in registers (row = lane&15, k = (lane>>4)*8 + j)
    bf16x8 qa0 = *reinterpret_cast<const bf16x8*>(&Q[base + (size_t)(qbase + l15) * DD + lhi * 8]);
    bf16x8 qa1 = *reinterpret_cast<const bf16x8*>(&Q[base + (size_t)(qbase + l15) * DD + 32 + lhi * 8]);

    f32x4 o[4] = {};          // output accum, d-groups of 16
    float mrow[4], lrow[4];   // per-lane: rows (lane>>4)*4 + r
    #pragma unroll
    for (int r = 0; r < 4; ++r) { mrow[r] = -1e30f; lrow[r] = 0.f; }

    const int ntiles = (q0 + 64) / 32;
    for (int kt = 0; kt < ntiles; ++kt) {
        const int k0 = kt * 32;
        __syncthreads();   // protect Vt against previous-iter readers
        {
            int kr = tid & 31, dc = tid >> 5;
            bf16x8 v = *reinterpret_cast<const bf16x8*>(&V[base + (size_t)(k0 + kr) * DD + dc * 8]);
            #pragma unroll
            for (int j = 0; j < 8; ++j) Vt[dc * 8 + j][kr] = v[j];
        }
        __syncthreads();

        if (k0 <= qbase + 15) {
            // QK^T: two 16-col groups
            f32x4 sc[2];
            #pragma unroll
            for (int g = 0; g < 2; ++g) {
                bf16x8 kb0 = *reinterpret_cast<const bf16x8*>(&K[base + (size_t)(k0 + g * 16 + l15) * DD + lhi * 8]);
                bf16x8 kb1 = *reinterpret_cast<const bf16x8*>(&K[base + (size_t)(k0 + g * 16 + l15) * DD + 32 + lhi * 8]);
                f32x4 c = {};
                c = __builtin_amdgcn_mfma_f32_16x16x32_bf16(qa0, kb0, c, 0, 0, 0);
                c = __builtin_amdgcn_mfma_f32_16x16x32_bf16(qa1, kb1, c, 0, 0, 0);
                sc[g] = c;
            }
            // causal mask (finite sentinel keeps exp math NaN-free)
            #pragma unroll
            for (int g = 0; g < 2; ++g) {
                int kcol = k0 + g * 16 + l15;
                #pragma unroll
                for (int r = 0; r < 4; ++r) {
                    int qrow = qbase + lhi * 4 + r;
                    if (kcol > qrow) sc[g][r] = -1e30f;
                }
            }
            // online softmax: row stats across lane&15 (16-lane groups)
            float tmax[4];
            #pragma unroll
            for (int r = 0; r < 4; ++r) tmax[r] = fmaxf(sc[0][r], sc[1][r]);
            #pragma unroll
            for (int msk = 1; msk < 16; msk <<= 1)
                #pragma unroll
                for (int r = 0; r < 4; ++r) tmax[r] = fmaxf(tmax[r], __shfl_xor(tmax[r], msk));
            float scal[4];
            #pragma unroll
            for (int r = 0; r < 4; ++r) {
                float mnew = fmaxf(mrow[r], tmax[r]);
                scal[r] = __expf(mrow[r] - mnew);
                mrow[r] = mnew;
            }
            #pragma unroll
            for (int g = 0; g < 2; ++g)
                #pragma unroll
                for (int r = 0; r < 4; ++r) sc[g][r] = __expf(sc[g][r] - mrow[r]);
            float tsum[4];
            #pragma unroll
            for (int r = 0; r < 4; ++r) tsum[r] = sc[0][r] + sc[1][r];
            #pragma unroll
            for (int msk = 1; msk < 16; msk <<= 1)
                #pragma unroll
                for (int r = 0; r < 4; ++r) tsum[r] += __shfl_xor(tsum[r], msk);
            #pragma unroll
            for (int r = 0; r < 4; ++r) lrow[r] = lrow[r] * scal[r] + tsum[r];
            // rescale O
            #pragma unroll
            for (int dg = 0; dg < 4; ++dg)
                #pragma unroll
                for (int r = 0; r < 4; ++r) o[dg][r] *= scal[r];
            // P -> LDS (per-wave region; in-wave DS order guarantees visibility)
            #pragma unroll
            for (int g = 0; g < 2; ++g)
                #pragma unroll
                for (int r = 0; r < 4; ++r)
                    Plds[wid][lhi * 4 + r][g * 16 + l15] = f2bf(sc[g][r]);
            bf16x8 pa = *reinterpret_cast<const bf16x8*>(&Plds[wid][l15][lhi * 8]);
            // PV: B-frag = Vt[d][kj]
            #pragma unroll
            for (int dg = 0; dg < 4; ++dg) {
                bf16x8 vb = *reinterpret_cast<const bf16x8*>(&Vt[dg * 16 + l15][lhi * 8]);
                o[dg] = __builtin_amdgcn_mfma_f32_16x16x32_bf16(pa, vb, o[dg], 0, 0, 0);
            }
        }
    }

    // epilogue: CTX[b][s][h*64+d] bf16
    const int b = bh >> 4, h = bh & 15;
    #pragma unroll
    for (int dg = 0; dg < 4; ++dg)
        #pragma unroll
        for (int r = 0; r < 4; ++r) {
            int s = qbase + lhi * 4 + r;
            float val = o[dg][r] / lrow[r];
            CTX[(size_t)(b * SS + s) * EE + h * DD + dg * 16 + l15] = f2bf(val);
        }
}

extern "C" void kernel_launch(void* const* d_in, const int* in_sizes, int n_in,
                              void* d_out, int out_size, void* d_ws, size_t ws_size,
                              hipStream_t stream) {
    const float* hs     = (const float*)d_in[0];  // [B,S,E]
    const float* attn_w = (const float*)d_in[1];  // [E,3E]
    const float* attn_b = (const float*)d_in[2];  // [3E]
    const float* proj_w = (const float*)d_in[3];  // [E,E]
    const float* proj_b = (const float*)d_in[4];  // [E]
    float* out = (float*)d_out;

    char* ws = (char*)d_ws;
    // byte offsets (all 256-aligned)
    short* Xb    = (short*)(ws + 0);          // 16.78 MB: X bf16 [8192][1024]; reused as CTX after attn
    short* Wqkv  = (short*)(ws + 16777216);   //  6.29 MB
    short* Wproj = (short*)(ws + 23068672);   //  2.10 MB
    short* Qb    = (short*)(ws + 25165824);   // 16.78 MB [B*H][S][D]
    short* Kb    = (short*)(ws + 41943040);   // 16.78 MB
    short* Vb    = (short*)(ws + 58720256);   // 16.78 MB
    short* CTX   = Xb;                        // X dead after QKV GEMM
    // total 75.5 MB

    cast_kernel<<<dim3(2048), dim3(256), 0, stream>>>(hs, Xb, (BB * SS * EE) / 4);
    cast_kernel<<<dim3(1024), dim3(256), 0, stream>>>(attn_w, Wqkv, (EE * 3 * EE) / 4);
    cast_kernel<<<dim3(512),  dim3(256), 0, stream>>>(proj_w, Wproj, (EE * EE) / 4);

    gemm_kernel<0, 3 * EE, EE><<<dim3(3 * EE / 128, BB * SS / 128), dim3(256), 0, stream>>>(
        Xb, Wqkv, attn_b, Qb, Kb, Vb, nullptr);

    attn_kernel<<<dim3(SS / 64, BB * HH), dim3(256), 0, stream>>>(Qb, Kb, Vb, CTX);

    gemm_kernel<1, EE, EE><<<dim3(EE / 128, BB * SS / 128), dim3(256), 0, stream>>>(
        CTX, Wproj, proj_b, nullptr, nullptr, nullptr, out);
}

// Round 3
// 235.182 us; speedup vs baseline: 2.7875x; 2.7875x over previous
//
#include <hip/hip_runtime.h>
#include <hip/hip_bf16.h>
#include <cstdint>
#include <cstddef>

// Problem constants
#define BB 4
#define SS 2048
#define EE 1024
#define HH 16
#define DD 64
// M = BB*SS = 8192

typedef __attribute__((ext_vector_type(8))) short bf16x8;
typedef __attribute__((ext_vector_type(4))) float f32x4;

__device__ __forceinline__ short f2bf(float f) {
    union { float f; uint32_t u; } x; x.f = f;
    uint32_t r = (x.u + 0x7fffu + ((x.u >> 16) & 1u)) >> 16;
    return (short)r;
}

// async global->LDS, 16B per lane. LDS dest must be wave-uniform base; HW adds lane*16.
__device__ __forceinline__ void gload16(const void* g, void* l) {
    __builtin_amdgcn_global_load_lds(
        (__attribute__((address_space(1))) uint32_t*)(uintptr_t)g,
        (__attribute__((address_space(3))) uint32_t*)(uint32_t)(uintptr_t)l,
        16, 0, 0);
}

__global__ void cast_kernel(const float* __restrict__ in, short* __restrict__ out, int n4) {
    int stride = gridDim.x * blockDim.x;
    for (int i = blockIdx.x * blockDim.x + threadIdx.x; i < n4; i += stride) {
        float4 v = reinterpret_cast<const float4*>(in)[i];
        short4 o;
        o.x = f2bf(v.x); o.y = f2bf(v.y); o.z = f2bf(v.z); o.w = f2bf(v.w);
        reinterpret_cast<short4*>(out)[i] = o;
    }
}

// in [K][N] f32 -> out [N][K] bf16 (weight transpose, runs once per call; tiny)
__global__ void transpose_cast_kernel(const float* __restrict__ in, short* __restrict__ out,
                                      int ncols, int nrows) {
    __shared__ float ts[32][33];
    const int t = threadIdx.x;
    const int r = t >> 3, c4 = (t & 7) * 4;
    const int n0 = blockIdx.x * 32, k0 = blockIdx.y * 32;
    float4 v = *reinterpret_cast<const float4*>(&in[(size_t)(k0 + r) * ncols + n0 + c4]);
    ts[c4 + 0][r] = v.x; ts[c4 + 1][r] = v.y; ts[c4 + 2][r] = v.z; ts[c4 + 3][r] = v.w;
    __syncthreads();
    short4 ov;
    ov.x = f2bf(ts[r][c4 + 0]); ov.y = f2bf(ts[r][c4 + 1]);
    ov.z = f2bf(ts[r][c4 + 2]); ov.w = f2bf(ts[r][c4 + 3]);
    *reinterpret_cast<short4*>(&out[(size_t)(n0 + r) * nrows + k0 + c4]) = ov;
}

// C = A[M,K=1024] * Bt[N,K]^T; 128x128 tile, 4 waves (2x2), wave 64x64 (4x4 frags 16x16x32)
// m97 structure: both tiles staged via global_load_lds dwordx4, linear LDS, 2 barriers/K-step.
// MODE 0: QKV epilogue (bias, Q*0.125, scatter to [B*H][S][D] bf16). MODE 1: fp32 out + bias.
template<int MODE, int N>
__global__ __launch_bounds__(256, 2)
void gemm_kernel(const short* __restrict__ A, const short* __restrict__ Bt,
                 const float* __restrict__ bias,
                 short* __restrict__ Qo, short* __restrict__ Ko, short* __restrict__ Vo,
                 float* __restrict__ Co)
{
    __shared__ short As[128][32];   // linear: row = 64B
    __shared__ short Bs[128][32];
    const int tid  = threadIdx.x;
    const int lane = tid & 63, wid = tid >> 6;
    const int wr = wid >> 1, wc = wid & 1;
    const int l15 = lane & 15, lhi = lane >> 4;
    const int m0 = blockIdx.y * 128, n0 = blockIdx.x * 128;
    const int sr  = lane >> 2;        // staging row within 16-row chunk
    const int sc8 = (lane & 3) * 8;   // staging col (elems)

    f32x4 acc[4][4] = {};

    for (int kt = 0; kt < EE / 32; ++kt) {
        __syncthreads();   // previous tile's readers done
        #pragma unroll
        for (int p = 0; p < 2; ++p) {
            const int c = wid * 2 + p;   // chunk: 16 rows = 1024B
            gload16(&A[(size_t)(m0 + c * 16 + sr) * EE + kt * 32 + sc8], &As[c * 16][0]);
            gload16(&Bt[(size_t)(n0 + c * 16 + sr) * EE + kt * 32 + sc8], &Bs[c * 16][0]);
        }
        __syncthreads();   // drains vmcnt (compiler-inserted)

        bf16x8 af[4], bfr[4];
        #pragma unroll
        for (int mm = 0; mm < 4; ++mm)
            af[mm] = *reinterpret_cast<const bf16x8*>(&As[wr * 64 + mm * 16 + l15][lhi * 8]);
        #pragma unroll
        for (int nn = 0; nn < 4; ++nn)
            bfr[nn] = *reinterpret_cast<const bf16x8*>(&Bs[wc * 64 + nn * 16 + l15][lhi * 8]);
        #pragma unroll
        for (int mm = 0; mm < 4; ++mm)
            #pragma unroll
            for (int nn = 0; nn < 4; ++nn)
                acc[mm][nn] = __builtin_amdgcn_mfma_f32_16x16x32_bf16(af[mm], bfr[nn], acc[mm][nn], 0, 0, 0);
    }

    // epilogue: C row = lhi*4 + r, col = l15 (m89-verified)
    #pragma unroll
    for (int mm = 0; mm < 4; ++mm) {
        #pragma unroll
        for (int nn = 0; nn < 4; ++nn) {
            int gcol = n0 + wc * 64 + nn * 16 + l15;
            float bv = bias[gcol];
            #pragma unroll
            for (int r = 0; r < 4; ++r) {
                int grow = m0 + wr * 64 + mm * 16 + lhi * 4 + r;
                float val = acc[mm][nn][r] + bv;
                if (MODE == 0) {
                    int part = gcol >> 10;       // 0=q 1=k 2=v
                    int e = gcol & 1023;
                    int h = e >> 6, d = e & 63;
                    int bidx = grow >> 11;
                    int s = grow & 2047;
                    size_t idx = ((size_t)(bidx * HH + h) * SS + s) * DD + d;
                    if (part == 0)      Qo[idx] = f2bf(val * 0.125f);  // fold 1/sqrt(D)
                    else if (part == 1) Ko[idx] = f2bf(val);
                    else                Vo[idx] = f2bf(val);
                } else {
                    Co[(size_t)grow * N + gcol] = val;
                }
            }
        }
    }
}

// Flash attention, causal-paired: block (pair, bh) handles q-tiles {pair, 31-pair} of 64 rows
// -> exactly 33 k-tiles of work per block (load-balanced). 4 waves x 16 q-rows per tile.
// KVBLK=64. K: global_load_lds with pre-swizzled source (conflict-free ds_read_b128).
// V: reg-staged (prefetched one tile ahead) -> transposed padded LDS.
__global__ __launch_bounds__(256, 2)
void attn_kernel(const short* __restrict__ Q, const short* __restrict__ K,
                 const short* __restrict__ V, short* __restrict__ CTX)
{
    __shared__ short Ks[64 * 64];       // linear, XOR-16B swizzled rows of 128B
    __shared__ short Vt[64][72];        // [d][k], pad 72
    __shared__ short Ps[4][16][72];     // per-wave P tile [q][k], pad 72
    const int tid  = threadIdx.x;
    const int lane = tid & 63, wid = tid >> 6;
    const int l15 = lane & 15, lhi = lane >> 4;
    const int bh = blockIdx.y;
    const int b = bh >> 4, h = bh & 15;
    const size_t base = (size_t)bh * (SS * DD);
    const int pair = blockIdx.x;

    // K staging geometry: chunk c (8 rows x 128B); lane -> row c*8 + (l>>3), 16B slot (l&7)
    // swizzled source col so that LDS[row][X] = K[row][X ^ ((row&7)<<4)]
    const int ksrow = lane >> 3;
    const int kscol = 8 * ((lane & 7) ^ (lane >> 3));   // elems (16B granule XOR row&7)
    // V staging: thread owns V row (tid&63), d-halves of its wave's 16-d group
    const int vkr = tid & 63, vg = wid;

    for (int phase = 0; phase < 2; ++phase) {
        const int t = phase ? (31 - pair) : pair;
        const int q0 = t * 64;
        const int qbase = q0 + wid * 16;

        bf16x8 qa[2];
        qa[0] = *reinterpret_cast<const bf16x8*>(&Q[base + (size_t)(qbase + l15) * DD + lhi * 8]);
        qa[1] = *reinterpret_cast<const bf16x8*>(&Q[base + (size_t)(qbase + l15) * DD + 32 + lhi * 8]);

        f32x4 o[4] = {};
        float mrow[4], lrow[4];
        #pragma unroll
        for (int r = 0; r < 4; ++r) { mrow[r] = -1e30f; lrow[r] = 0.f; }

        // prefetch V regs for kt=0
        bf16x8 vr0 = *reinterpret_cast<const bf16x8*>(&V[base + (size_t)vkr * DD + vg * 16]);
        bf16x8 vr1 = *reinterpret_cast<const bf16x8*>(&V[base + (size_t)vkr * DD + vg * 16 + 8]);

        for (int kt = 0; kt <= t; ++kt) {
            const int k0 = kt * 64;
            __syncthreads();   // previous tile's LDS readers done
            // stage K via async gload (2 chunks/wave)
            #pragma unroll
            for (int p = 0; p < 2; ++p) {
                const int c = wid * 2 + p;
                gload16(&K[base + (size_t)(k0 + c * 8 + ksrow) * DD + kscol],
                        (char*)Ks + c * 1024);
            }
            // V transpose write from prefetched regs
            #pragma unroll
            for (int j = 0; j < 8; ++j) Vt[vg * 16 + j][vkr] = vr0[j];
            #pragma unroll
            for (int j = 0; j < 8; ++j) Vt[vg * 16 + 8 + j][vkr] = vr1[j];
            // issue next tile's V loads (latency hides under compute below)
            if (kt < t) {
                vr0 = *reinterpret_cast<const bf16x8*>(&V[base + (size_t)(k0 + 64 + vkr) * DD + vg * 16]);
                vr1 = *reinterpret_cast<const bf16x8*>(&V[base + (size_t)(k0 + 64 + vkr) * DD + vg * 16 + 8]);
            }
            __syncthreads();   // staging visible

            // QK^T: 4 col-groups x 2 k-steps; swizzled Ks read (conflict-free)
            f32x4 sc[4];
            #pragma unroll
            for (int n = 0; n < 4; ++n) {
                const int row = n * 16 + l15;
                f32x4 cacc = {};
                #pragma unroll
                for (int ks = 0; ks < 2; ++ks) {
                    // K byte offset wanted: elem (ks*32 + lhi*8) -> byte ks*64 + lhi*16
                    const int byteoff = (ks * 64 + lhi * 16) ^ ((l15 & 7) << 4);
                    bf16x8 kb = *reinterpret_cast<const bf16x8*>((const char*)Ks + row * 128 + byteoff);
                    cacc = __builtin_amdgcn_mfma_f32_16x16x32_bf16(qa[ks], kb, cacc, 0, 0, 0);
                }
                sc[n] = cacc;
            }
            // causal mask only on the diagonal tile (k0 == q0)
            if (kt == t) {
                #pragma unroll
                for (int n = 0; n < 4; ++n) {
                    const int col = n * 16 + l15;
                    #pragma unroll
                    for (int r = 0; r < 4; ++r) {
                        const int qrow = wid * 16 + lhi * 4 + r;
                        if (col > qrow) sc[n][r] = -1e30f;
                    }
                }
            }
            // online softmax over 64 cols (16-lane-group shuffle reduce)
            float tmax[4];
            #pragma unroll
            for (int r = 0; r < 4; ++r)
                tmax[r] = fmaxf(fmaxf(sc[0][r], sc[1][r]), fmaxf(sc[2][r], sc[3][r]));
            #pragma unroll
            for (int msk = 1; msk < 16; msk <<= 1)
                #pragma unroll
                for (int r = 0; r < 4; ++r) tmax[r] = fmaxf(tmax[r], __shfl_xor(tmax[r], msk));
            float scal[4];
            #pragma unroll
            for (int r = 0; r < 4; ++r) {
                float mnew = fmaxf(mrow[r], tmax[r]);
                scal[r] = __expf(mrow[r] - mnew);
                mrow[r] = mnew;
            }
            #pragma unroll
            for (int n = 0; n < 4; ++n)
                #pragma unroll
                for (int r = 0; r < 4; ++r) sc[n][r] = __expf(sc[n][r] - mrow[r]);
            float tsum[4];
            #pragma unroll
            for (int r = 0; r < 4; ++r)
                tsum[r] = (sc[0][r] + sc[1][r]) + (sc[2][r] + sc[3][r]);
            #pragma unroll
            for (int msk = 1; msk < 16; msk <<= 1)
                #pragma unroll
                for (int r = 0; r < 4; ++r) tsum[r] += __shfl_xor(tsum[r], msk);
            #pragma unroll
            for (int r = 0; r < 4; ++r) lrow[r] = lrow[r] * scal[r] + tsum[r];
            #pragma unroll
            for (int dg = 0; dg < 4; ++dg)
                #pragma unroll
                for (int r = 0; r < 4; ++r) o[dg][r] *= scal[r];
            // P -> per-wave LDS (in-wave DS ordering), then A-frags
            #pragma unroll
            for (int n = 0; n < 4; ++n)
                #pragma unroll
                for (int r = 0; r < 4; ++r)
                    Ps[wid][lhi * 4 + r][n * 16 + l15] = f2bf(sc[n][r]);
            bf16x8 pa[2];
            pa[0] = *reinterpret_cast<const bf16x8*>(&Ps[wid][l15][lhi * 8]);
            pa[1] = *reinterpret_cast<const bf16x8*>(&Ps[wid][l15][32 + lhi * 8]);
            // PV
            #pragma unroll
            for (int dg = 0; dg < 4; ++dg) {
                #pragma unroll
                for (int ks = 0; ks < 2; ++ks) {
                    bf16x8 vb = *reinterpret_cast<const bf16x8*>(&Vt[dg * 16 + l15][ks * 32 + lhi * 8]);
                    o[dg] = __builtin_amdgcn_mfma_f32_16x16x32_bf16(pa[ks], vb, o[dg], 0, 0, 0);
                }
            }
        }

        // epilogue: CTX[b][s][h*64+d] bf16
        #pragma unroll
        for (int dg = 0; dg < 4; ++dg)
            #pragma unroll
            for (int r = 0; r < 4; ++r) {
                int s = qbase + lhi * 4 + r;
                float val = o[dg][r] / lrow[r];
                CTX[(size_t)(b * SS + s) * EE + h * DD + dg * 16 + l15] = f2bf(val);
            }
    }
}

extern "C" void kernel_launch(void* const* d_in, const int* in_sizes, int n_in,
                              void* d_out, int out_size, void* d_ws, size_t ws_size,
                              hipStream_t stream) {
    const float* hs     = (const float*)d_in[0];  // [B,S,E]
    const float* attn_w = (const float*)d_in[1];  // [E,3E]
    const float* attn_b = (const float*)d_in[2];  // [3E]
    const float* proj_w = (const float*)d_in[3];  // [E,E]
    const float* proj_b = (const float*)d_in[4];  // [E]
    float* out = (float*)d_out;

    char* ws = (char*)d_ws;
    short* Xb    = (short*)(ws + 0);          // 16.78 MB bf16 X; reused as CTX
    short* WqkvT = (short*)(ws + 16777216);   //  6.29 MB [3E][E] bf16
    short* WprojT= (short*)(ws + 23068672);   //  2.10 MB [E][E] bf16
    short* Qb    = (short*)(ws + 25165824);   // 16.78 MB [B*H][S][D]
    short* Kb    = (short*)(ws + 41943040);   // 16.78 MB
    short* Vb    = (short*)(ws + 58720256);   // 16.78 MB
    short* CTX   = Xb;

    cast_kernel<<<dim3(2048), dim3(256), 0, stream>>>(hs, Xb, (BB * SS * EE) / 4);
    transpose_cast_kernel<<<dim3(3 * EE / 32, EE / 32), dim3(256), 0, stream>>>(attn_w, WqkvT, 3 * EE, EE);
    transpose_cast_kernel<<<dim3(EE / 32, EE / 32), dim3(256), 0, stream>>>(proj_w, WprojT, EE, EE);

    gemm_kernel<0, 3 * EE><<<dim3(3 * EE / 128, BB * SS / 128), dim3(256), 0, stream>>>(
        Xb, WqkvT, attn_b, Qb, Kb, Vb, nullptr);

    attn_kernel<<<dim3(16, BB * HH), dim3(256), 0, stream>>>(Qb, Kb, Vb, CTX);

    gemm_kernel<1, EE><<<dim3(EE / 128, BB * SS / 128), dim3(256), 0, stream>>>(
        CTX, WprojT, proj_b, nullptr, nullptr, nullptr, out);
}

// Round 4
// 225.203 us; speedup vs baseline: 2.9110x; 1.0443x over previous
//
#include <hip/hip_runtime.h>
#include <hip/hip_bf16.h>
#include <cstdint>
#include <cstddef>

// Problem constants
#define BB 4
#define SS 2048
#define EE 1024
#define HH 16
#define DD 64
// M = BB*SS = 8192

typedef __attribute__((ext_vector_type(8))) short bf16x8;
typedef __attribute__((ext_vector_type(4))) float f32x4;

__device__ __forceinline__ short f2bf(float f) {          // RNE
    union { float f; uint32_t u; } x; x.f = f;
    uint32_t r = (x.u + 0x7fffu + ((x.u >> 16) & 1u)) >> 16;
    return (short)r;
}
__device__ __forceinline__ short f2bf_fast(float f) {     // round-half-up, for P>=0 only
    union { float f; uint32_t u; } x; x.f = f;
    return (short)((x.u + 0x8000u) >> 16);
}

// async global->LDS, 16B per lane. LDS dest wave-uniform base; HW adds lane*16.
__device__ __forceinline__ void gload16(const void* g, void* l) {
    __builtin_amdgcn_global_load_lds(
        (__attribute__((address_space(1))) uint32_t*)(uintptr_t)g,
        (__attribute__((address_space(3))) uint32_t*)(uint32_t)(uintptr_t)l,
        16, 0, 0);
}

// DPP lane move within 16-lane rows (VALU latency, no LDS)
template<int CTRL>
__device__ __forceinline__ float dppmove(float v) {
    return __int_as_float(__builtin_amdgcn_update_dpp(
        0, __float_as_int(v), CTRL, 0xf, 0xf, true));
}
// full 16-lane row reduce: xor1, xor2, then ror4+ror8 complete the tree
#define ROW_REDUCE(vals, OP)                                             \
    _Pragma("unroll") for (int _r = 0; _r < 4; ++_r) {                   \
        vals[_r] = OP(vals[_r], dppmove<0xB1>(vals[_r]));                \
        vals[_r] = OP(vals[_r], dppmove<0x4E>(vals[_r]));                \
        vals[_r] = OP(vals[_r], dppmove<0x124>(vals[_r]));               \
        vals[_r] = OP(vals[_r], dppmove<0x128>(vals[_r]));               \
    }
__device__ __forceinline__ float opmax(float a, float b) { return fmaxf(a, b); }
__device__ __forceinline__ float opsum(float a, float b) { return a + b; }

__global__ void cast_kernel(const float* __restrict__ in, short* __restrict__ out, int n4) {
    int stride = gridDim.x * blockDim.x;
    for (int i = blockIdx.x * blockDim.x + threadIdx.x; i < n4; i += stride) {
        float4 v = reinterpret_cast<const float4*>(in)[i];
        short4 o;
        o.x = f2bf(v.x); o.y = f2bf(v.y); o.z = f2bf(v.z); o.w = f2bf(v.w);
        reinterpret_cast<short4*>(out)[i] = o;
    }
}

// in [K][N] f32 -> out [N][K] bf16 (weight transpose; tiny)
__global__ void transpose_cast_kernel(const float* __restrict__ in, short* __restrict__ out,
                                      int ncols, int nrows) {
    __shared__ float ts[32][33];
    const int t = threadIdx.x;
    const int r = t >> 3, c4 = (t & 7) * 4;
    const int n0 = blockIdx.x * 32, k0 = blockIdx.y * 32;
    float4 v = *reinterpret_cast<const float4*>(&in[(size_t)(k0 + r) * ncols + n0 + c4]);
    ts[c4 + 0][r] = v.x; ts[c4 + 1][r] = v.y; ts[c4 + 2][r] = v.z; ts[c4 + 3][r] = v.w;
    __syncthreads();
    short4 ov;
    ov.x = f2bf(ts[r][c4 + 0]); ov.y = f2bf(ts[r][c4 + 1]);
    ov.z = f2bf(ts[r][c4 + 2]); ov.w = f2bf(ts[r][c4 + 3]);
    *reinterpret_cast<short4*>(&out[(size_t)(n0 + r) * nrows + k0 + c4]) = ov;
}

// C = A[M,K=1024] * Bt[N,K]^T; 128x128 tile, 4 waves (2x2), wave 64x64 (4x4 frags 16x16x32)
// MODE 0: QKV epilogue (bias, Q*0.125, scatter; V stored TRANSPOSED [bh][D][S]). MODE 1: fp32+bias.
template<int MODE, int N>
__global__ __launch_bounds__(256, 2)
void gemm_kernel(const short* __restrict__ A, const short* __restrict__ Bt,
                 const float* __restrict__ bias,
                 short* __restrict__ Qo, short* __restrict__ Ko, short* __restrict__ Vo,
                 float* __restrict__ Co)
{
    __shared__ short As[128][32];
    __shared__ short Bs[128][32];
    const int tid  = threadIdx.x;
    const int lane = tid & 63, wid = tid >> 6;
    const int wr = wid >> 1, wc = wid & 1;
    const int l15 = lane & 15, lhi = lane >> 4;
    const int m0 = blockIdx.y * 128, n0 = blockIdx.x * 128;
    const int sr  = lane >> 2;
    const int sc8 = (lane & 3) * 8;

    f32x4 acc[4][4] = {};

    for (int kt = 0; kt < EE / 32; ++kt) {
        __syncthreads();
        #pragma unroll
        for (int p = 0; p < 2; ++p) {
            const int c = wid * 2 + p;
            gload16(&A[(size_t)(m0 + c * 16 + sr) * EE + kt * 32 + sc8], &As[c * 16][0]);
            gload16(&Bt[(size_t)(n0 + c * 16 + sr) * EE + kt * 32 + sc8], &Bs[c * 16][0]);
        }
        __syncthreads();

        bf16x8 af[4], bfr[4];
        #pragma unroll
        for (int mm = 0; mm < 4; ++mm)
            af[mm] = *reinterpret_cast<const bf16x8*>(&As[wr * 64 + mm * 16 + l15][lhi * 8]);
        #pragma unroll
        for (int nn = 0; nn < 4; ++nn)
            bfr[nn] = *reinterpret_cast<const bf16x8*>(&Bs[wc * 64 + nn * 16 + l15][lhi * 8]);
        #pragma unroll
        for (int mm = 0; mm < 4; ++mm)
            #pragma unroll
            for (int nn = 0; nn < 4; ++nn)
                acc[mm][nn] = __builtin_amdgcn_mfma_f32_16x16x32_bf16(af[mm], bfr[nn], acc[mm][nn], 0, 0, 0);
    }

    #pragma unroll
    for (int mm = 0; mm < 4; ++mm) {
        #pragma unroll
        for (int nn = 0; nn < 4; ++nn) {
            int gcol = n0 + wc * 64 + nn * 16 + l15;
            float bv = bias[gcol];
            #pragma unroll
            for (int r = 0; r < 4; ++r) {
                int grow = m0 + wr * 64 + mm * 16 + lhi * 4 + r;
                float val = acc[mm][nn][r] + bv;
                if (MODE == 0) {
                    int part = gcol >> 10;       // 0=q 1=k 2=v
                    int e = gcol & 1023;
                    int h = e >> 6, d = e & 63;
                    int bidx = grow >> 11;
                    int s = grow & 2047;
                    int bh = bidx * HH + h;
                    if (part == 0)
                        Qo[((size_t)bh * SS + s) * DD + d] = f2bf(val * 0.125f);
                    else if (part == 1)
                        Ko[((size_t)bh * SS + s) * DD + d] = f2bf(val);
                    else  // V transposed: [bh][D][S]
                        Vo[((size_t)bh * DD + d) * SS + s] = f2bf(val);
                } else {
                    Co[(size_t)grow * N + gcol] = val;
                }
            }
        }
    }
}

// Flash attention, causal-paired + XCD-swizzled. Block handles q-tiles {pair, 31-pair} (33 k-tiles).
// 4 waves x 16 q-rows. KVBLK=64. K [bh][S][D] and V^T [bh][D][S] both staged via swizzled
// global_load_lds, double-buffered, ONE barrier per tile (stage kt+1 before computing kt).
__global__ __launch_bounds__(256, 2)
void attn_kernel(const short* __restrict__ Q, const short* __restrict__ K,
                 const short* __restrict__ Vt, short* __restrict__ CTX)
{
    __shared__ short Ks[2][4096];   // 64 rows x 128B, XOR-16B swizzled
    __shared__ short Vs[2][4096];   // 64 d-rows x 128B, XOR-16B swizzled
    __shared__ short Ps[4][16][72]; // per-wave P [q][k]
    const int tid  = threadIdx.x;
    const int lane = tid & 63, wid = tid >> 6;
    const int l15 = lane & 15, lhi = lane >> 4;
    // XCD swizzle: all 16 pair-blocks of one bh land on one XCD; 8 heads per XCD (4MB L2)
    const int bid  = blockIdx.x;
    const int bh   = (bid & 7) * 8 + ((bid >> 3) & 7);
    const int pair = bid >> 6;
    const int b = bh >> 4, h = bh & 15;
    const size_t base = (size_t)bh * (SS * DD);

    // staging geometry: chunk c = wid*2+p covers 8 rows x 128B; lane -> row c*8+(l>>3),
    // 16B slot (l&7), source col XOR'd so LDS[row][X] = src[row][X ^ ((row&7)<<4)]
    const int srow = lane >> 3;
    const int scol = 8 * ((lane & 7) ^ srow);   // elems

    for (int phase = 0; phase < 2; ++phase) {
        const int t = phase ? (31 - pair) : pair;
        const int q0 = t * 64;
        const int qbase = q0 + wid * 16;

        bf16x8 qa[2];
        qa[0] = *reinterpret_cast<const bf16x8*>(&Q[base + (size_t)(qbase + l15) * DD + lhi * 8]);
        qa[1] = *reinterpret_cast<const bf16x8*>(&Q[base + (size_t)(qbase + l15) * DD + 32 + lhi * 8]);

        f32x4 o[4] = {};
        float mrow[4], lrow[4];
        #pragma unroll
        for (int r = 0; r < 4; ++r) { mrow[r] = -1e30f; lrow[r] = 0.f; }

        // prologue: stage tile 0 into buf 0 (safe: previous phase's last-tile barrier passed)
        #pragma unroll
        for (int p = 0; p < 2; ++p) {
            const int c = wid * 2 + p;
            gload16(&K [base + (size_t)(c * 8 + srow) * DD + scol], &Ks[0][c * 512]);
            gload16(&Vt[base + (size_t)(c * 8 + srow) * SS + scol], &Vs[0][c * 512]);
        }
        __syncthreads();   // drains vmcnt: tile 0 ready

        for (int kt = 0; kt <= t; ++kt) {
            const int cur = kt & 1;
            // stage NEXT tile (latency hides under this tile's compute)
            if (kt < t) {
                const int k1 = (kt + 1) * 64;
                #pragma unroll
                for (int p = 0; p < 2; ++p) {
                    const int c = wid * 2 + p;
                    gload16(&K [base + (size_t)(k1 + c * 8 + srow) * DD + scol], &Ks[cur ^ 1][c * 512]);
                    gload16(&Vt[base + (size_t)(c * 8 + srow) * SS + k1 + scol], &Vs[cur ^ 1][c * 512]);
                }
            }

            // QK^T: 4 col-groups x 2 k-steps (swizzled conflict-free ds_read_b128)
            f32x4 sc[4];
            #pragma unroll
            for (int n = 0; n < 4; ++n) {
                const int row = n * 16 + l15;
                f32x4 cacc = {};
                #pragma unroll
                for (int ks = 0; ks < 2; ++ks) {
                    const int byteoff = (ks * 64 + lhi * 16) ^ ((l15 & 7) << 4);
                    bf16x8 kb = *reinterpret_cast<const bf16x8*>((const char*)&Ks[cur][0] + row * 128 + byteoff);
                    cacc = __builtin_amdgcn_mfma_f32_16x16x32_bf16(qa[ks], kb, cacc, 0, 0, 0);
                }
                sc[n] = cacc;
            }
            // causal mask on diagonal tile only
            if (kt == t) {
                #pragma unroll
                for (int n = 0; n < 4; ++n) {
                    const int col = n * 16 + l15;
                    #pragma unroll
                    for (int r = 0; r < 4; ++r) {
                        const int qrow = wid * 16 + lhi * 4 + r;
                        if (col > qrow) sc[n][r] = -1e30f;
                    }
                }
            }
            // online softmax; row reduce via DPP (VALU latency, no LDS)
            float tmax[4];
            #pragma unroll
            for (int r = 0; r < 4; ++r)
                tmax[r] = fmaxf(fmaxf(sc[0][r], sc[1][r]), fmaxf(sc[2][r], sc[3][r]));
            ROW_REDUCE(tmax, opmax)
            float scal[4];
            #pragma unroll
            for (int r = 0; r < 4; ++r) {
                float mnew = fmaxf(mrow[r], tmax[r]);
                scal[r] = __expf(mrow[r] - mnew);
                mrow[r] = mnew;
            }
            #pragma unroll
            for (int n = 0; n < 4; ++n)
                #pragma unroll
                for (int r = 0; r < 4; ++r) sc[n][r] = __expf(sc[n][r] - mrow[r]);
            float tsum[4];
            #pragma unroll
            for (int r = 0; r < 4; ++r)
                tsum[r] = (sc[0][r] + sc[1][r]) + (sc[2][r] + sc[3][r]);
            ROW_REDUCE(tsum, opsum)
            #pragma unroll
            for (int r = 0; r < 4; ++r) lrow[r] = lrow[r] * scal[r] + tsum[r];
            #pragma unroll
            for (int dg = 0; dg < 4; ++dg)
                #pragma unroll
                for (int r = 0; r < 4; ++r) o[dg][r] *= scal[r];
            // P -> per-wave LDS (in-wave DS ordering), then A-frags
            #pragma unroll
            for (int n = 0; n < 4; ++n)
                #pragma unroll
                for (int r = 0; r < 4; ++r)
                    Ps[wid][lhi * 4 + r][n * 16 + l15] = f2bf_fast(sc[n][r]);
            bf16x8 pa[2];
            pa[0] = *reinterpret_cast<const bf16x8*>(&Ps[wid][l15][lhi * 8]);
            pa[1] = *reinterpret_cast<const bf16x8*>(&Ps[wid][l15][32 + lhi * 8]);
            // PV from V^T tile (same swizzle as K)
            #pragma unroll
            for (int dg = 0; dg < 4; ++dg) {
                const int row = dg * 16 + l15;
                #pragma unroll
                for (int ks = 0; ks < 2; ++ks) {
                    const int byteoff = (ks * 64 + lhi * 16) ^ ((l15 & 7) << 4);
                    bf16x8 vb = *reinterpret_cast<const bf16x8*>((const char*)&Vs[cur][0] + row * 128 + byteoff);
                    o[dg] = __builtin_amdgcn_mfma_f32_16x16x32_bf16(pa[ks], vb, o[dg], 0, 0, 0);
                }
            }
            __syncthreads();   // readers done with buf[cur]; next tile's gloads drained
        }

        // epilogue: CTX[b][s][h*64+d] bf16
        #pragma unroll
        for (int dg = 0; dg < 4; ++dg)
            #pragma unroll
            for (int r = 0; r < 4; ++r) {
                int s = qbase + lhi * 4 + r;
                float val = o[dg][r] / lrow[r];
                CTX[(size_t)(b * SS + s) * EE + h * DD + dg * 16 + l15] = f2bf(val);
            }
    }
}

extern "C" void kernel_launch(void* const* d_in, const int* in_sizes, int n_in,
                              void* d_out, int out_size, void* d_ws, size_t ws_size,
                              hipStream_t stream) {
    const float* hs     = (const float*)d_in[0];  // [B,S,E]
    const float* attn_w = (const float*)d_in[1];  // [E,3E]
    const float* attn_b = (const float*)d_in[2];  // [3E]
    const float* proj_w = (const float*)d_in[3];  // [E,E]
    const float* proj_b = (const float*)d_in[4];  // [E]
    float* out = (float*)d_out;

    char* ws = (char*)d_ws;
    short* Xb    = (short*)(ws + 0);          // 16.78 MB bf16 X; reused as CTX
    short* WqkvT = (short*)(ws + 16777216);   //  6.29 MB [3E][E] bf16
    short* WprojT= (short*)(ws + 23068672);   //  2.10 MB [E][E] bf16
    short* Qb    = (short*)(ws + 25165824);   // 16.78 MB [B*H][S][D]
    short* Kb    = (short*)(ws + 41943040);   // 16.78 MB [B*H][S][D]
    short* Vb    = (short*)(ws + 58720256);   // 16.78 MB [B*H][D][S]  (transposed)
    short* CTX   = Xb;

    cast_kernel<<<dim3(2048), dim3(256), 0, stream>>>(hs, Xb, (BB * SS * EE) / 4);
    transpose_cast_kernel<<<dim3(3 * EE / 32, EE / 32), dim3(256), 0, stream>>>(attn_w, WqkvT, 3 * EE, EE);
    transpose_cast_kernel<<<dim3(EE / 32, EE / 32), dim3(256), 0, stream>>>(proj_w, WprojT, EE, EE);

    gemm_kernel<0, 3 * EE><<<dim3(3 * EE / 128, BB * SS / 128), dim3(256), 0, stream>>>(
        Xb, WqkvT, attn_b, Qb, Kb, Vb, nullptr);

    attn_kernel<<<dim3(1024), dim3(256), 0, stream>>>(Qb, Kb, Vb, CTX);

    gemm_kernel<1, EE><<<dim3(EE / 128, BB * SS / 128), dim3(256), 0, stream>>>(
        CTX, WprojT, proj_b, nullptr, nullptr, nullptr, out);
}

// Round 5
// 203.180 us; speedup vs baseline: 3.2265x; 1.1084x over previous
//
#include <hip/hip_runtime.h>
#include <hip/hip_bf16.h>
#include <cstdint>
#include <cstddef>

// Problem constants
#define BB 4
#define SS 2048
#define EE 1024
#define HH 16
#define DD 64
// M = BB*SS = 8192

typedef __attribute__((ext_vector_type(8))) short bf16x8;
typedef __attribute__((ext_vector_type(4))) float f32x4;

__device__ __forceinline__ short f2bf(float f) {          // RNE
    union { float f; uint32_t u; } x; x.f = f;
    uint32_t r = (x.u + 0x7fffu + ((x.u >> 16) & 1u)) >> 16;
    return (short)r;
}
__device__ __forceinline__ short f2bf_fast(float f) {     // round-half-up, for P>=0 only
    union { float f; uint32_t u; } x; x.f = f;
    return (short)((x.u + 0x8000u) >> 16);
}

// async global->LDS, 16B per lane. LDS dest wave-uniform base; HW adds lane*16.
__device__ __forceinline__ void gload16(const void* g, void* l) {
    __builtin_amdgcn_global_load_lds(
        (__attribute__((address_space(1))) uint32_t*)(uintptr_t)g,
        (__attribute__((address_space(3))) uint32_t*)(uint32_t)(uintptr_t)l,
        16, 0, 0);
}

// DPP lane move within 16-lane rows (VALU latency, no LDS)
template<int CTRL>
__device__ __forceinline__ float dppmove(float v) {
    return __int_as_float(__builtin_amdgcn_update_dpp(
        0, __float_as_int(v), CTRL, 0xf, 0xf, true));
}
// full 16-lane row reduce: xor1, xor2, then ror4+ror8 complete the tree
#define ROW_REDUCE(vals, OP)                                             \
    _Pragma("unroll") for (int _r = 0; _r < 4; ++_r) {                   \
        vals[_r] = OP(vals[_r], dppmove<0xB1>(vals[_r]));                \
        vals[_r] = OP(vals[_r], dppmove<0x4E>(vals[_r]));                \
        vals[_r] = OP(vals[_r], dppmove<0x124>(vals[_r]));               \
        vals[_r] = OP(vals[_r], dppmove<0x128>(vals[_r]));               \
    }
__device__ __forceinline__ float opmax(float a, float b) { return fmaxf(a, b); }
__device__ __forceinline__ float opsum(float a, float b) { return a + b; }

__global__ void cast_kernel(const float* __restrict__ in, short* __restrict__ out, int n4) {
    int stride = gridDim.x * blockDim.x;
    for (int i = blockIdx.x * blockDim.x + threadIdx.x; i < n4; i += stride) {
        float4 v = reinterpret_cast<const float4*>(in)[i];
        short4 o;
        o.x = f2bf(v.x); o.y = f2bf(v.y); o.z = f2bf(v.z); o.w = f2bf(v.w);
        reinterpret_cast<short4*>(out)[i] = o;
    }
}

// in [K][N] f32 -> out [N][K] bf16 (weight transpose; tiny)
__global__ void transpose_cast_kernel(const float* __restrict__ in, short* __restrict__ out,
                                      int ncols, int nrows) {
    __shared__ float ts[32][33];
    const int t = threadIdx.x;
    const int r = t >> 3, c4 = (t & 7) * 4;
    const int n0 = blockIdx.x * 32, k0 = blockIdx.y * 32;
    float4 v = *reinterpret_cast<const float4*>(&in[(size_t)(k0 + r) * ncols + n0 + c4]);
    ts[c4 + 0][r] = v.x; ts[c4 + 1][r] = v.y; ts[c4 + 2][r] = v.z; ts[c4 + 3][r] = v.w;
    __syncthreads();
    short4 ov;
    ov.x = f2bf(ts[r][c4 + 0]); ov.y = f2bf(ts[r][c4 + 1]);
    ov.z = f2bf(ts[r][c4 + 2]); ov.w = f2bf(ts[r][c4 + 3]);
    *reinterpret_cast<short4*>(&out[(size_t)(n0 + r) * nrows + k0 + c4]) = ov;
}

// C = A[M,K=1024] * Bt[N,K]^T; 128x128 tile, 4 waves (2x2), wave 64x64 (4x4 frags 16x16x32).
// Double-buffered LDS + next-tile prefetch (minimum 2-phase): stage kt+1 before computing kt,
// ONE barrier per iteration -> global latency hides under MFMA+ds_read.
// MODE 0: QKV epilogue (bias, Q*0.125; V stored TRANSPOSED [bh][D][S], packed 8B stores).
// MODE 1: fp32 out + bias.
template<int MODE, int N>
__global__ __launch_bounds__(256, 2)
void gemm_kernel(const short* __restrict__ A, const short* __restrict__ Bt,
                 const float* __restrict__ bias,
                 short* __restrict__ Qo, short* __restrict__ Ko, short* __restrict__ Vo,
                 float* __restrict__ Co)
{
    __shared__ short As[2][4096];   // [buf][row*32+k], rows of 64B, linear
    __shared__ short Bs[2][4096];
    const int tid  = threadIdx.x;
    const int lane = tid & 63, wid = tid >> 6;
    const int wr = wid >> 1, wc = wid & 1;
    const int l15 = lane & 15, lhi = lane >> 4;
    const int m0 = blockIdx.y * 128, n0 = blockIdx.x * 128;
    const int sr  = lane >> 2;        // staging row within 16-row chunk
    const int sc8 = (lane & 3) * 8;   // staging col (elems)

    f32x4 acc[4][4] = {};

    // prologue: stage tile 0 into buf 0
    #pragma unroll
    for (int p = 0; p < 2; ++p) {
        const int c = wid * 2 + p;
        gload16(&A [(size_t)(m0 + c * 16 + sr) * EE + sc8], &As[0][c * 512]);
        gload16(&Bt[(size_t)(n0 + c * 16 + sr) * EE + sc8], &Bs[0][c * 512]);
    }
    __syncthreads();   // vmcnt(0) drained: tile 0 ready

    for (int kt = 0; kt < EE / 32; ++kt) {
        const int cur = kt & 1;
        // prefetch NEXT K-tile into the other buffer (latency hides under compute)
        if (kt < EE / 32 - 1) {
            const int kk = (kt + 1) * 32;
            #pragma unroll
            for (int p = 0; p < 2; ++p) {
                const int c = wid * 2 + p;
                gload16(&A [(size_t)(m0 + c * 16 + sr) * EE + kk + sc8], &As[cur ^ 1][c * 512]);
                gload16(&Bt[(size_t)(n0 + c * 16 + sr) * EE + kk + sc8], &Bs[cur ^ 1][c * 512]);
            }
        }

        bf16x8 af[4], bfr[4];
        #pragma unroll
        for (int mm = 0; mm < 4; ++mm)
            af[mm] = *reinterpret_cast<const bf16x8*>(&As[cur][(wr * 64 + mm * 16 + l15) * 32 + lhi * 8]);
        #pragma unroll
        for (int nn = 0; nn < 4; ++nn)
            bfr[nn] = *reinterpret_cast<const bf16x8*>(&Bs[cur][(wc * 64 + nn * 16 + l15) * 32 + lhi * 8]);
        #pragma unroll
        for (int mm = 0; mm < 4; ++mm)
            #pragma unroll
            for (int nn = 0; nn < 4; ++nn)
                acc[mm][nn] = __builtin_amdgcn_mfma_f32_16x16x32_bf16(af[mm], bfr[nn], acc[mm][nn], 0, 0, 0);

        __syncthreads();   // readers done with buf[cur]; prefetch into buf[cur^1] drained
    }

    if (MODE == 0) {
        const int part = n0 >> 10;   // block-uniform: 0=q 1=k 2=v
        #pragma unroll
        for (int mm = 0; mm < 4; ++mm) {
            #pragma unroll
            for (int nn = 0; nn < 4; ++nn) {
                const int gcol = n0 + wc * 64 + nn * 16 + l15;
                const float bv = bias[gcol];
                const int e = gcol & 1023;
                const int h = e >> 6, d = e & 63;
                const int grow0 = m0 + wr * 64 + mm * 16 + lhi * 4;  // 4 consecutive rows, same b
                const int bidx = grow0 >> 11;
                const int s0 = grow0 & 2047;
                const int bh = bidx * HH + h;
                if (part == 2) {
                    // V^T [bh][D][S]: 4 consecutive s -> one 8B store
                    short4 pk;
                    pk.x = f2bf(acc[mm][nn][0] + bv);
                    pk.y = f2bf(acc[mm][nn][1] + bv);
                    pk.z = f2bf(acc[mm][nn][2] + bv);
                    pk.w = f2bf(acc[mm][nn][3] + bv);
                    *reinterpret_cast<short4*>(&Vo[((size_t)bh * DD + d) * SS + s0]) = pk;
                } else if (part == 0) {
                    #pragma unroll
                    for (int r = 0; r < 4; ++r)
                        Qo[((size_t)bh * SS + s0 + r) * DD + d] = f2bf((acc[mm][nn][r] + bv) * 0.125f);
                } else {
                    #pragma unroll
                    for (int r = 0; r < 4; ++r)
                        Ko[((size_t)bh * SS + s0 + r) * DD + d] = f2bf(acc[mm][nn][r] + bv);
                }
            }
        }
    } else {
        #pragma unroll
        for (int mm = 0; mm < 4; ++mm) {
            #pragma unroll
            for (int nn = 0; nn < 4; ++nn) {
                const int gcol = n0 + wc * 64 + nn * 16 + l15;
                const float bv = bias[gcol];
                #pragma unroll
                for (int r = 0; r < 4; ++r) {
                    const int grow = m0 + wr * 64 + mm * 16 + lhi * 4 + r;
                    Co[(size_t)grow * N + gcol] = acc[mm][nn][r] + bv;
                }
            }
        }
    }
}

// Flash attention, causal-paired + XCD-swizzled. Block handles q-tiles {pair, 31-pair} (33 k-tiles).
// 4 waves x 16 q-rows. KVBLK=64. K [bh][S][D] and V^T [bh][D][S] both staged via swizzled
// global_load_lds, double-buffered, ONE barrier per tile (stage kt+1 before computing kt).
__global__ __launch_bounds__(256, 2)
void attn_kernel(const short* __restrict__ Q, const short* __restrict__ K,
                 const short* __restrict__ Vt, short* __restrict__ CTX)
{
    __shared__ short Ks[2][4096];   // 64 rows x 128B, XOR-16B swizzled
    __shared__ short Vs[2][4096];   // 64 d-rows x 128B, XOR-16B swizzled
    __shared__ short Ps[4][16][72]; // per-wave P [q][k]
    const int tid  = threadIdx.x;
    const int lane = tid & 63, wid = tid >> 6;
    const int l15 = lane & 15, lhi = lane >> 4;
    // XCD swizzle: all 16 pair-blocks of one bh land on one XCD; 8 heads per XCD (4MB L2)
    const int bid  = blockIdx.x;
    const int bh   = (bid & 7) * 8 + ((bid >> 3) & 7);
    const int pair = bid >> 6;
    const int b = bh >> 4, h = bh & 15;
    const size_t base = (size_t)bh * (SS * DD);

    // staging geometry: chunk c = wid*2+p covers 8 rows x 128B; lane -> row c*8+(l>>3),
    // 16B slot (l&7), source col XOR'd so LDS[row][X] = src[row][X ^ ((row&7)<<4)]
    const int srow = lane >> 3;
    const int scol = 8 * ((lane & 7) ^ srow);   // elems

    for (int phase = 0; phase < 2; ++phase) {
        const int t = phase ? (31 - pair) : pair;
        const int q0 = t * 64;
        const int qbase = q0 + wid * 16;

        bf16x8 qa[2];
        qa[0] = *reinterpret_cast<const bf16x8*>(&Q[base + (size_t)(qbase + l15) * DD + lhi * 8]);
        qa[1] = *reinterpret_cast<const bf16x8*>(&Q[base + (size_t)(qbase + l15) * DD + 32 + lhi * 8]);

        f32x4 o[4] = {};
        float mrow[4], lrow[4];
        #pragma unroll
        for (int r = 0; r < 4; ++r) { mrow[r] = -1e30f; lrow[r] = 0.f; }

        // prologue: stage tile 0 into buf 0 (safe: previous phase's last-tile barrier passed)
        #pragma unroll
        for (int p = 0; p < 2; ++p) {
            const int c = wid * 2 + p;
            gload16(&K [base + (size_t)(c * 8 + srow) * DD + scol], &Ks[0][c * 512]);
            gload16(&Vt[base + (size_t)(c * 8 + srow) * SS + scol], &Vs[0][c * 512]);
        }
        __syncthreads();   // drains vmcnt: tile 0 ready

        for (int kt = 0; kt <= t; ++kt) {
            const int cur = kt & 1;
            // stage NEXT tile (latency hides under this tile's compute)
            if (kt < t) {
                const int k1 = (kt + 1) * 64;
                #pragma unroll
                for (int p = 0; p < 2; ++p) {
                    const int c = wid * 2 + p;
                    gload16(&K [base + (size_t)(k1 + c * 8 + srow) * DD + scol], &Ks[cur ^ 1][c * 512]);
                    gload16(&Vt[base + (size_t)(c * 8 + srow) * SS + k1 + scol], &Vs[cur ^ 1][c * 512]);
                }
            }

            // QK^T: 4 col-groups x 2 k-steps (swizzled conflict-free ds_read_b128)
            f32x4 sc[4];
            #pragma unroll
            for (int n = 0; n < 4; ++n) {
                const int row = n * 16 + l15;
                f32x4 cacc = {};
                #pragma unroll
                for (int ks = 0; ks < 2; ++ks) {
                    const int byteoff = (ks * 64 + lhi * 16) ^ ((l15 & 7) << 4);
                    bf16x8 kb = *reinterpret_cast<const bf16x8*>((const char*)&Ks[cur][0] + row * 128 + byteoff);
                    cacc = __builtin_amdgcn_mfma_f32_16x16x32_bf16(qa[ks], kb, cacc, 0, 0, 0);
                }
                sc[n] = cacc;
            }
            // causal mask on diagonal tile only
            if (kt == t) {
                #pragma unroll
                for (int n = 0; n < 4; ++n) {
                    const int col = n * 16 + l15;
                    #pragma unroll
                    for (int r = 0; r < 4; ++r) {
                        const int qrow = wid * 16 + lhi * 4 + r;
                        if (col > qrow) sc[n][r] = -1e30f;
                    }
                }
            }
            // online softmax; row reduce via DPP (VALU latency, no LDS)
            float tmax[4];
            #pragma unroll
            for (int r = 0; r < 4; ++r)
                tmax[r] = fmaxf(fmaxf(sc[0][r], sc[1][r]), fmaxf(sc[2][r], sc[3][r]));
            ROW_REDUCE(tmax, opmax)
            float scal[4];
            #pragma unroll
            for (int r = 0; r < 4; ++r) {
                float mnew = fmaxf(mrow[r], tmax[r]);
                scal[r] = __expf(mrow[r] - mnew);
                mrow[r] = mnew;
            }
            #pragma unroll
            for (int n = 0; n < 4; ++n)
                #pragma unroll
                for (int r = 0; r < 4; ++r) sc[n][r] = __expf(sc[n][r] - mrow[r]);
            float tsum[4];
            #pragma unroll
            for (int r = 0; r < 4; ++r)
                tsum[r] = (sc[0][r] + sc[1][r]) + (sc[2][r] + sc[3][r]);
            ROW_REDUCE(tsum, opsum)
            #pragma unroll
            for (int r = 0; r < 4; ++r) lrow[r] = lrow[r] * scal[r] + tsum[r];
            #pragma unroll
            for (int dg = 0; dg < 4; ++dg)
                #pragma unroll
                for (int r = 0; r < 4; ++r) o[dg][r] *= scal[r];
            // P -> per-wave LDS (in-wave DS ordering), then A-frags
            #pragma unroll
            for (int n = 0; n < 4; ++n)
                #pragma unroll
                for (int r = 0; r < 4; ++r)
                    Ps[wid][lhi * 4 + r][n * 16 + l15] = f2bf_fast(sc[n][r]);
            bf16x8 pa[2];
            pa[0] = *reinterpret_cast<const bf16x8*>(&Ps[wid][l15][lhi * 8]);
            pa[1] = *reinterpret_cast<const bf16x8*>(&Ps[wid][l15][32 + lhi * 8]);
            // PV from V^T tile (same swizzle as K)
            #pragma unroll
            for (int dg = 0; dg < 4; ++dg) {
                const int row = dg * 16 + l15;
                #pragma unroll
                for (int ks = 0; ks < 2; ++ks) {
                    const int byteoff = (ks * 64 + lhi * 16) ^ ((l15 & 7) << 4);
                    bf16x8 vb = *reinterpret_cast<const bf16x8*>((const char*)&Vs[cur][0] + row * 128 + byteoff);
                    o[dg] = __builtin_amdgcn_mfma_f32_16x16x32_bf16(pa[ks], vb, o[dg], 0, 0, 0);
                }
            }
            __syncthreads();   // readers done with buf[cur]; next tile's gloads drained
        }

        // epilogue: CTX[b][s][h*64+d] bf16
        #pragma unroll
        for (int dg = 0; dg < 4; ++dg)
            #pragma unroll
            for (int r = 0; r < 4; ++r) {
                int s = qbase + lhi * 4 + r;
                float val = o[dg][r] / lrow[r];
                CTX[(size_t)(b * SS + s) * EE + h * DD + dg * 16 + l15] = f2bf(val);
            }
    }
}

extern "C" void kernel_launch(void* const* d_in, const int* in_sizes, int n_in,
                              void* d_out, int out_size, void* d_ws, size_t ws_size,
                              hipStream_t stream) {
    const float* hs     = (const float*)d_in[0];  // [B,S,E]
    const float* attn_w = (const float*)d_in[1];  // [E,3E]
    const float* attn_b = (const float*)d_in[2];  // [3E]
    const float* proj_w = (const float*)d_in[3];  // [E,E]
    const float* proj_b = (const float*)d_in[4];  // [E]
    float* out = (float*)d_out;

    char* ws = (char*)d_ws;
    short* Xb    = (short*)(ws + 0);          // 16.78 MB bf16 X; reused as CTX
    short* WqkvT = (short*)(ws + 16777216);   //  6.29 MB [3E][E] bf16
    short* WprojT= (short*)(ws + 23068672);   //  2.10 MB [E][E] bf16
    short* Qb    = (short*)(ws + 25165824);   // 16.78 MB [B*H][S][D]
    short* Kb    = (short*)(ws + 41943040);   // 16.78 MB [B*H][S][D]
    short* Vb    = (short*)(ws + 58720256);   // 16.78 MB [B*H][D][S]  (transposed)
    short* CTX   = Xb;

    cast_kernel<<<dim3(2048), dim3(256), 0, stream>>>(hs, Xb, (BB * SS * EE) / 4);
    transpose_cast_kernel<<<dim3(3 * EE / 32, EE / 32), dim3(256), 0, stream>>>(attn_w, WqkvT, 3 * EE, EE);
    transpose_cast_kernel<<<dim3(EE / 32, EE / 32), dim3(256), 0, stream>>>(proj_w, WprojT, EE, EE);

    gemm_kernel<0, 3 * EE><<<dim3(3 * EE / 128, BB * SS / 128), dim3(256), 0, stream>>>(
        Xb, WqkvT, attn_b, Qb, Kb, Vb, nullptr);

    attn_kernel<<<dim3(1024), dim3(256), 0, stream>>>(Qb, Kb, Vb, CTX);

    gemm_kernel<1, EE><<<dim3(EE / 128, BB * SS / 128), dim3(256), 0, stream>>>(
        CTX, WprojT, proj_b, nullptr, nullptr, nullptr, out);
}